// Round 1
// baseline (4924.309 us; speedup 1.0000x reference)
//
#include <hip/hip_runtime.h>

// 3-layer GraphConv + set pooling + MLP head, f32 throughout.
// Strategy: atomic scatter-add aggregation, LDS-staged dense transform, fused MLP.

#define FEAT 64

// ---------------- scatter: agg[dst] += h[src], 64 f32 per edge ----------------
// 16 threads per edge, float4 gather, 4 f32 atomics per thread.
__global__ void scatter_add_kernel(const float* __restrict__ h,
                                   const int* __restrict__ src,
                                   const int* __restrict__ dst,
                                   float* __restrict__ agg,
                                   int nedges) {
  int idx = blockIdx.x * blockDim.x + threadIdx.x;
  int e = idx >> 4;
  if (e >= nedges) return;
  int c = idx & 15;
  int s = src[e];
  int d = dst[e];
  float4 v = ((const float4*)(h + (size_t)s * FEAT))[c];
  float* ap = agg + (size_t)d * FEAT + c * 4;
  atomicAdd(ap + 0, v.x);
  atomicAdd(ap + 1, v.y);
  atomicAdd(ap + 2, v.z);
  atomicAdd(ap + 3, v.w);
}

// ---------------- dense transform: out = elu(h@w_root + agg@w_rel + b) -------
// Block = 256 threads = 4 nodes x 64 out-features. Weights + rows staged in LDS.
__global__ void conv_transform_kernel(const float* __restrict__ h,
                                      const float* __restrict__ agg,
                                      const float* __restrict__ w_root,
                                      const float* __restrict__ w_rel,
                                      const float* __restrict__ bias,
                                      float* __restrict__ out,
                                      int n) {
  __shared__ float s_wroot[FEAT * FEAT];
  __shared__ float s_wrel[FEAT * FEAT];
  __shared__ float s_b[FEAT];
  __shared__ float s_h[4][FEAT];
  __shared__ float s_a[4][FEAT];
  int tid = threadIdx.x;
  for (int i = tid; i < FEAT * FEAT; i += 256) {
    s_wroot[i] = w_root[i];
    s_wrel[i] = w_rel[i];
  }
  if (tid < FEAT) s_b[tid] = bias[tid];
  __syncthreads();

  int ln = tid >> 6;   // node slot 0..3 (one wave per node)
  int j = tid & 63;    // output feature

  for (int base = blockIdx.x * 4; base < n; base += gridDim.x * 4) {
    int node = base + ln;
    if (node < n) {
      s_h[ln][j] = h[(size_t)node * FEAT + j];
      s_a[ln][j] = agg[(size_t)node * FEAT + j];
    }
    __syncthreads();
    if (node < n) {
      float acc = s_b[j];
#pragma unroll
      for (int k = 0; k < FEAT; ++k) {
        acc += s_h[ln][k] * s_wroot[k * FEAT + j] + s_a[ln][k] * s_wrel[k * FEAT + j];
      }
      out[(size_t)node * FEAT + j] = acc > 0.f ? acc : (__expf(acc) - 1.f);
    }
    __syncthreads();
  }
}

// ---------------- MLP head: elu(fc1) -> elu(fc2) -> fc3 -> log_softmax -------
// Block = 256 threads = 4 sets x 64 lanes.
__global__ void mlp_head_kernel(const float* __restrict__ pooled,
                                const float* __restrict__ fc1_w, const float* __restrict__ fc1_b,
                                const float* __restrict__ fc2_w, const float* __restrict__ fc2_b,
                                const float* __restrict__ fc3_w, const float* __restrict__ fc3_b,
                                float* __restrict__ out, int nsets) {
  __shared__ float s_p[4][FEAT];
  __shared__ float s_t1[4][FEAT];
  __shared__ float s_t2[4][32];
  int tid = threadIdx.x;
  int ln = tid >> 6;
  int j = tid & 63;
  int s = blockIdx.x * 4 + ln;

  if (s < nsets) s_p[ln][j] = pooled[(size_t)s * FEAT + j];
  __syncthreads();

  if (s < nsets) {
    float acc = fc1_b[j];
#pragma unroll
    for (int k = 0; k < FEAT; ++k) acc += s_p[ln][k] * fc1_w[k * FEAT + j];
    s_t1[ln][j] = acc > 0.f ? acc : (__expf(acc) - 1.f);
  }
  __syncthreads();

  if (s < nsets && j < 32) {
    float acc = fc2_b[j];
#pragma unroll
    for (int k = 0; k < FEAT; ++k) acc += s_t1[ln][k] * fc2_w[k * 32 + j];
    s_t2[ln][j] = acc > 0.f ? acc : (__expf(acc) - 1.f);
  }
  __syncthreads();

  if (s < nsets && j < 2) {
    float a0 = fc3_b[0], a1 = fc3_b[1];
#pragma unroll
    for (int k = 0; k < 32; ++k) {
      float t = s_t2[ln][k];
      a0 += t * fc3_w[k * 2 + 0];
      a1 += t * fc3_w[k * 2 + 1];
    }
    float m = fmaxf(a0, a1);
    float lse = m + logf(__expf(a0 - m) + __expf(a1 - m));
    out[(size_t)s * 2 + j] = (j == 0 ? a0 : a1) - lse;
  }
}

extern "C" void kernel_launch(void* const* d_in, const int* in_sizes, int n_in,
                              void* d_out, int out_size, void* d_ws, size_t ws_size,
                              hipStream_t stream) {
  const float* x        = (const float*)d_in[0];
  const int* edge_src   = (const int*)d_in[1];
  const int* edge_dst   = (const int*)d_in[2];
  const int* gather_idx = (const int*)d_in[3];
  const int* seg_idx    = (const int*)d_in[4];
  const float* w_root0  = (const float*)d_in[5];
  const float* w_rel0   = (const float*)d_in[6];
  const float* b0       = (const float*)d_in[7];
  const float* w_root_h = (const float*)d_in[8];
  const float* w_rel_h  = (const float*)d_in[9];
  const float* b_h      = (const float*)d_in[10];
  const float* fc1_w    = (const float*)d_in[11];
  const float* fc1_b    = (const float*)d_in[12];
  const float* fc2_w    = (const float*)d_in[13];
  const float* fc2_b    = (const float*)d_in[14];
  const float* fc3_w    = (const float*)d_in[15];
  const float* fc3_b    = (const float*)d_in[16];

  const int N = in_sizes[0] / FEAT;
  const int E = in_sizes[1];
  const int A = in_sizes[3];
  const int S = out_size / 2;

  size_t row_bytes = (size_t)N * FEAT * sizeof(float);
  char* ws = (char*)d_ws;
  float* agg    = (float*)(ws);
  float* hA     = (float*)(ws + row_bytes);
  float* hB     = (float*)(ws + 2 * row_bytes);
  float* pooled = (float*)(ws + 3 * row_bytes);

  dim3 blk(256);
  int scatter_grid = (int)(((size_t)E * 16 + 255) / 256);
  int pool_grid    = (int)(((size_t)A * 16 + 255) / 256);
  int tgrid = 2048;

  // ---- layer 0: input x ----
  hipMemsetAsync(agg, 0, row_bytes, stream);
  scatter_add_kernel<<<scatter_grid, blk, 0, stream>>>(x, edge_src, edge_dst, agg, E);
  conv_transform_kernel<<<tgrid, blk, 0, stream>>>(x, agg, w_root0, w_rel0, b0, hA, N);

  // ---- layer 1 ----
  hipMemsetAsync(agg, 0, row_bytes, stream);
  scatter_add_kernel<<<scatter_grid, blk, 0, stream>>>(hA, edge_src, edge_dst, agg, E);
  conv_transform_kernel<<<tgrid, blk, 0, stream>>>(hA, agg, w_root_h, w_rel_h, b_h, hB, N);

  // ---- layer 2 ----
  hipMemsetAsync(agg, 0, row_bytes, stream);
  scatter_add_kernel<<<scatter_grid, blk, 0, stream>>>(hB, edge_src, edge_dst, agg, E);
  conv_transform_kernel<<<tgrid, blk, 0, stream>>>(hB, agg, w_root_h + FEAT * FEAT, w_rel_h + FEAT * FEAT,
                                                   b_h + FEAT, hA, N);

  // ---- set pooling ----
  hipMemsetAsync(pooled, 0, (size_t)S * FEAT * sizeof(float), stream);
  scatter_add_kernel<<<pool_grid, blk, 0, stream>>>(hA, gather_idx, seg_idx, pooled, A);

  // ---- MLP head + log_softmax ----
  mlp_head_kernel<<<(S + 3) / 4, blk, 0, stream>>>(pooled, fc1_w, fc1_b, fc2_w, fc2_b,
                                                   fc3_w, fc3_b, (float*)d_out, S);
}

// Round 2
// 874.392 us; speedup vs baseline: 5.6317x; 5.6317x over previous
//
#include <hip/hip_runtime.h>

// 3-layer GraphConv + set pooling + MLP head, f32 throughout.
// R2: replace float-atomic scatter (102M atomics, 4.1ms) with per-call CSR build
// (int atomics only) + gather-based aggregation (one wave per dst node).

#define FEAT 64
#define SCHUNK 1024

// ---------------- CSR build ----------------
__global__ void count_kernel(const int* __restrict__ dst, int* __restrict__ deg, int n) {
  int i = blockIdx.x * 256 + threadIdx.x;
  if (i < n) atomicAdd(&deg[dst[i]], 1);
}

// per-chunk exclusive scan (chunk = 1024 = 256 threads x 4), block totals to bsums
__global__ void scan1_kernel(const int* __restrict__ in, int* __restrict__ out,
                             int* __restrict__ bsums, int n) {
  __shared__ int tsum[256];
  int tid = threadIdx.x;
  int base = blockIdx.x * SCHUNK + tid * 4;
  int v[4];
#pragma unroll
  for (int i = 0; i < 4; ++i) v[i] = (base + i < n) ? in[base + i] : 0;
  int local = v[0] + v[1] + v[2] + v[3];
  tsum[tid] = local;
  __syncthreads();
  for (int off = 1; off < 256; off <<= 1) {
    int u = (tid >= off) ? tsum[tid - off] : 0;
    __syncthreads();
    tsum[tid] += u;
    __syncthreads();
  }
  int excl = tsum[tid] - local;
  if (tid == 255) bsums[blockIdx.x] = tsum[255];
  int run = excl;
#pragma unroll
  for (int i = 0; i < 4; ++i) {
    if (base + i < n) out[base + i] = run;
    run += v[i];
  }
}

// single-block exclusive scan of block sums (nb <= 256)
__global__ void scan2_kernel(int* __restrict__ bsums, int nb) {
  __shared__ int t[256];
  int tid = threadIdx.x;
  int v = (tid < nb) ? bsums[tid] : 0;
  t[tid] = v;
  __syncthreads();
  for (int off = 1; off < 256; off <<= 1) {
    int u = (tid >= off) ? t[tid - off] : 0;
    __syncthreads();
    t[tid] += u;
    __syncthreads();
  }
  if (tid < nb) bsums[tid] = t[tid] - v;
}

// add chunk offsets; write row_start and a cursor copy for the fill pass
__global__ void scan3_kernel(int* __restrict__ row_start, const int* __restrict__ bsums,
                             int* __restrict__ cursor, int n) {
  int i = blockIdx.x * 256 + threadIdx.x;
  if (i < n) {
    int v = row_start[i] + bsums[i / SCHUNK];
    row_start[i] = v;
    cursor[i] = v;
  }
}

__global__ void fill_kernel(const int* __restrict__ src, const int* __restrict__ dst,
                            int* __restrict__ cursor, int* __restrict__ csr, int n) {
  int i = blockIdx.x * 256 + threadIdx.x;
  if (i < n) {
    int p = atomicAdd(&cursor[dst[i]], 1);
    csr[p] = src[i];
  }
}

// ---------------- gather aggregation: agg[node] = sum_{e in row} h[csr[e]] ----
// One wave per node; lane j holds feature j. Node index is wave-uniform.
__global__ void gather_agg_kernel(const float* __restrict__ h,
                                  const int* __restrict__ row_start,
                                  const int* __restrict__ deg,
                                  const int* __restrict__ csr,
                                  float* __restrict__ agg, int n) {
  int node = blockIdx.x * 4 + (threadIdx.x >> 6);
  if (node >= n) return;
  int j = threadIdx.x & 63;
  int beg = row_start[node];
  int d = deg[node];
  float acc = 0.f;
  int i = 0;
  for (; i + 3 < d; i += 4) {
    int s0 = csr[beg + i];
    int s1 = csr[beg + i + 1];
    int s2 = csr[beg + i + 2];
    int s3 = csr[beg + i + 3];
    float v0 = h[(size_t)s0 * FEAT + j];
    float v1 = h[(size_t)s1 * FEAT + j];
    float v2 = h[(size_t)s2 * FEAT + j];
    float v3 = h[(size_t)s3 * FEAT + j];
    acc += v0 + v1 + v2 + v3;
  }
  for (; i < d; ++i) {
    int s = csr[beg + i];
    acc += h[(size_t)s * FEAT + j];
  }
  agg[(size_t)node * FEAT + j] = acc;
}

// ---------------- dense transform: out = elu(h@w_root + agg@w_rel + b) -------
// Safe for out == agg (each block only rewrites rows it already read).
__global__ void conv_transform_kernel(const float* __restrict__ h,
                                      const float* __restrict__ agg,
                                      const float* __restrict__ w_root,
                                      const float* __restrict__ w_rel,
                                      const float* __restrict__ bias,
                                      float* __restrict__ out,
                                      int n) {
  __shared__ float s_wroot[FEAT * FEAT];
  __shared__ float s_wrel[FEAT * FEAT];
  __shared__ float s_b[FEAT];
  __shared__ float s_h[4][FEAT];
  __shared__ float s_a[4][FEAT];
  int tid = threadIdx.x;
  for (int i = tid; i < FEAT * FEAT; i += 256) {
    s_wroot[i] = w_root[i];
    s_wrel[i] = w_rel[i];
  }
  if (tid < FEAT) s_b[tid] = bias[tid];
  __syncthreads();

  int ln = tid >> 6;
  int j = tid & 63;

  for (int base = blockIdx.x * 4; base < n; base += gridDim.x * 4) {
    int node = base + ln;
    if (node < n) {
      s_h[ln][j] = h[(size_t)node * FEAT + j];
      s_a[ln][j] = agg[(size_t)node * FEAT + j];
    }
    __syncthreads();
    if (node < n) {
      float acc = s_b[j];
#pragma unroll
      for (int k = 0; k < FEAT; ++k) {
        acc += s_h[ln][k] * s_wroot[k * FEAT + j] + s_a[ln][k] * s_wrel[k * FEAT + j];
      }
      out[(size_t)node * FEAT + j] = acc > 0.f ? acc : (__expf(acc) - 1.f);
    }
    __syncthreads();
  }
}

// ---------------- MLP head: elu(fc1) -> elu(fc2) -> fc3 -> log_softmax -------
__global__ void mlp_head_kernel(const float* __restrict__ pooled,
                                const float* __restrict__ fc1_w, const float* __restrict__ fc1_b,
                                const float* __restrict__ fc2_w, const float* __restrict__ fc2_b,
                                const float* __restrict__ fc3_w, const float* __restrict__ fc3_b,
                                float* __restrict__ out, int nsets) {
  __shared__ float s_p[4][FEAT];
  __shared__ float s_t1[4][FEAT];
  __shared__ float s_t2[4][32];
  int tid = threadIdx.x;
  int ln = tid >> 6;
  int j = tid & 63;
  int s = blockIdx.x * 4 + ln;

  if (s < nsets) s_p[ln][j] = pooled[(size_t)s * FEAT + j];
  __syncthreads();

  if (s < nsets) {
    float acc = fc1_b[j];
#pragma unroll
    for (int k = 0; k < FEAT; ++k) acc += s_p[ln][k] * fc1_w[k * FEAT + j];
    s_t1[ln][j] = acc > 0.f ? acc : (__expf(acc) - 1.f);
  }
  __syncthreads();

  if (s < nsets && j < 32) {
    float acc = fc2_b[j];
#pragma unroll
    for (int k = 0; k < FEAT; ++k) acc += s_t1[ln][k] * fc2_w[k * 32 + j];
    s_t2[ln][j] = acc > 0.f ? acc : (__expf(acc) - 1.f);
  }
  __syncthreads();

  if (s < nsets && j < 2) {
    float a0 = fc3_b[0], a1 = fc3_b[1];
#pragma unroll
    for (int k = 0; k < 32; ++k) {
      float t = s_t2[ln][k];
      a0 += t * fc3_w[k * 2 + 0];
      a1 += t * fc3_w[k * 2 + 1];
    }
    float m = fmaxf(a0, a1);
    float lse = m + logf(__expf(a0 - m) + __expf(a1 - m));
    out[(size_t)s * 2 + j] = (j == 0 ? a0 : a1) - lse;
  }
}

extern "C" void kernel_launch(void* const* d_in, const int* in_sizes, int n_in,
                              void* d_out, int out_size, void* d_ws, size_t ws_size,
                              hipStream_t stream) {
  const float* x        = (const float*)d_in[0];
  const int* edge_src   = (const int*)d_in[1];
  const int* edge_dst   = (const int*)d_in[2];
  const int* gather_idx = (const int*)d_in[3];
  const int* seg_idx    = (const int*)d_in[4];
  const float* w_root0  = (const float*)d_in[5];
  const float* w_rel0   = (const float*)d_in[6];
  const float* b0       = (const float*)d_in[7];
  const float* w_root_h = (const float*)d_in[8];
  const float* w_rel_h  = (const float*)d_in[9];
  const float* b_h      = (const float*)d_in[10];
  const float* fc1_w    = (const float*)d_in[11];
  const float* fc1_b    = (const float*)d_in[12];
  const float* fc2_w    = (const float*)d_in[13];
  const float* fc2_b    = (const float*)d_in[14];
  const float* fc3_w    = (const float*)d_in[15];
  const float* fc3_b    = (const float*)d_in[16];

  const int N = in_sizes[0] / FEAT;
  const int E = in_sizes[1];
  const int A = in_sizes[3];
  const int S = out_size / 2;

  size_t row_bytes  = (size_t)N * FEAT * sizeof(float);   // 25.6 MB
  size_t pool_bytes = (size_t)S * FEAT * sizeof(float);   // 12.8 MB

  char* ws = (char*)d_ws;
  size_t off = 0;
  float* buf1   = (float*)(ws + off); off += row_bytes;
  float* buf2   = (float*)(ws + off); off += row_bytes;
  float* pooled = (float*)(ws + off); off += pool_bytes;
  int* csr_e    = (int*)(ws + off); off += (size_t)E * 4;
  int* deg_e    = (int*)(ws + off); off += (size_t)N * 4;
  int* rs_e     = (int*)(ws + off); off += (size_t)N * 4;
  int* cur_e    = (int*)(ws + off); off += (size_t)N * 4;
  int* csr_p    = (int*)(ws + off); off += (size_t)A * 4;
  int* deg_p    = (int*)(ws + off); off += (size_t)S * 4;
  int* rs_p     = (int*)(ws + off); off += (size_t)S * 4;
  int* cur_p    = (int*)(ws + off); off += (size_t)S * 4;
  int* bsums_e  = (int*)(ws + off); off += 256 * 4;
  int* bsums_p  = (int*)(ws + off); off += 256 * 4;

  dim3 blk(256);
  int nb_e = (N + SCHUNK - 1) / SCHUNK;   // 98
  int nb_p = (S + SCHUNK - 1) / SCHUNK;   // 49

  // ---- build edge CSR (dst-major) ----
  hipMemsetAsync(deg_e, 0, (size_t)N * 4, stream);
  count_kernel<<<(E + 255) / 256, blk, 0, stream>>>(edge_dst, deg_e, E);
  scan1_kernel<<<nb_e, blk, 0, stream>>>(deg_e, rs_e, bsums_e, N);
  scan2_kernel<<<1, blk, 0, stream>>>(bsums_e, nb_e);
  scan3_kernel<<<(N + 255) / 256, blk, 0, stream>>>(rs_e, bsums_e, cur_e, N);
  fill_kernel<<<(E + 255) / 256, blk, 0, stream>>>(edge_src, edge_dst, cur_e, csr_e, E);

  // ---- build pool CSR (seg-major) ----
  hipMemsetAsync(deg_p, 0, (size_t)S * 4, stream);
  count_kernel<<<(A + 255) / 256, blk, 0, stream>>>(seg_idx, deg_p, A);
  scan1_kernel<<<nb_p, blk, 0, stream>>>(deg_p, rs_p, bsums_p, S);
  scan2_kernel<<<1, blk, 0, stream>>>(bsums_p, nb_p);
  scan3_kernel<<<(S + 255) / 256, blk, 0, stream>>>(rs_p, bsums_p, cur_p, S);
  fill_kernel<<<(A + 255) / 256, blk, 0, stream>>>(gather_idx, seg_idx, cur_p, csr_p, A);

  int agg_grid  = (N + 3) / 4;
  int pool_grid = (S + 3) / 4;
  int tgrid = 2048;

  // ---- layer 0: aggregate(x) -> buf1; transform(x, buf1) -> buf1 (in place) ----
  gather_agg_kernel<<<agg_grid, blk, 0, stream>>>(x, rs_e, deg_e, csr_e, buf1, N);
  conv_transform_kernel<<<tgrid, blk, 0, stream>>>(x, buf1, w_root0, w_rel0, b0, buf1, N);

  // ---- layer 1 ----
  gather_agg_kernel<<<agg_grid, blk, 0, stream>>>(buf1, rs_e, deg_e, csr_e, buf2, N);
  conv_transform_kernel<<<tgrid, blk, 0, stream>>>(buf1, buf2, w_root_h, w_rel_h, b_h, buf2, N);

  // ---- layer 2 ----
  gather_agg_kernel<<<agg_grid, blk, 0, stream>>>(buf2, rs_e, deg_e, csr_e, buf1, N);
  conv_transform_kernel<<<tgrid, blk, 0, stream>>>(buf2, buf1, w_root_h + FEAT * FEAT,
                                                   w_rel_h + FEAT * FEAT, b_h + FEAT, buf1, N);

  // ---- set pooling: gather-sum h3 rows into pooled ----
  gather_agg_kernel<<<pool_grid, blk, 0, stream>>>(buf1, rs_p, deg_p, csr_p, pooled, S);

  // ---- MLP head + log_softmax ----
  mlp_head_kernel<<<(S + 3) / 4, blk, 0, stream>>>(pooled, fc1_w, fc1_b, fc2_w, fc2_b,
                                                   fc3_w, fc3_b, (float*)d_out, S);
}

// Round 3
// 742.543 us; speedup vs baseline: 6.6317x; 1.1776x over previous
//
#include <hip/hip_runtime.h>

// 3-layer GraphConv + set pooling + MLP head, f32 throughout.
// R3: fuse gather+transform per layer (agg never leaves LDS); lane=node
// register-tiled transform with wave-uniform scalar weight loads; fused
// pooling+MLP. CSR build unchanged from R2.

#define FEAT 64
#define SCHUNK 1024
#define STRIDE 68   // 64 + 4 pad: 16B-aligned rows, conflict-balanced b128

// ---------------- CSR build ----------------
__global__ void count_kernel(const int* __restrict__ dst, int* __restrict__ deg, int n) {
  int i = blockIdx.x * 256 + threadIdx.x;
  if (i < n) atomicAdd(&deg[dst[i]], 1);
}

__global__ void scan1_kernel(const int* __restrict__ in, int* __restrict__ out,
                             int* __restrict__ bsums, int n) {
  __shared__ int tsum[256];
  int tid = threadIdx.x;
  int base = blockIdx.x * SCHUNK + tid * 4;
  int v[4];
#pragma unroll
  for (int i = 0; i < 4; ++i) v[i] = (base + i < n) ? in[base + i] : 0;
  int local = v[0] + v[1] + v[2] + v[3];
  tsum[tid] = local;
  __syncthreads();
  for (int off = 1; off < 256; off <<= 1) {
    int u = (tid >= off) ? tsum[tid - off] : 0;
    __syncthreads();
    tsum[tid] += u;
    __syncthreads();
  }
  int excl = tsum[tid] - local;
  if (tid == 255) bsums[blockIdx.x] = tsum[255];
  int run = excl;
#pragma unroll
  for (int i = 0; i < 4; ++i) {
    if (base + i < n) out[base + i] = run;
    run += v[i];
  }
}

__global__ void scan2_kernel(int* __restrict__ bsums, int nb) {
  __shared__ int t[256];
  int tid = threadIdx.x;
  int v = (tid < nb) ? bsums[tid] : 0;
  t[tid] = v;
  __syncthreads();
  for (int off = 1; off < 256; off <<= 1) {
    int u = (tid >= off) ? t[tid - off] : 0;
    __syncthreads();
    t[tid] += u;
    __syncthreads();
  }
  if (tid < nb) bsums[tid] = t[tid] - v;
}

__global__ void scan3_kernel(int* __restrict__ row_start, const int* __restrict__ bsums,
                             int* __restrict__ cursor, int n) {
  int i = blockIdx.x * 256 + threadIdx.x;
  if (i < n) {
    int v = row_start[i] + bsums[i / SCHUNK];
    row_start[i] = v;
    cursor[i] = v;
  }
}

__global__ void fill_kernel(const int* __restrict__ src, const int* __restrict__ dst,
                            int* __restrict__ cursor, int* __restrict__ csr, int n) {
  int i = blockIdx.x * 256 + threadIdx.x;
  if (i < n) {
    int p = atomicAdd(&cursor[dst[i]], 1);
    csr[p] = src[i];
  }
}

// ---------------- helpers ----------------
__device__ __forceinline__ float4 reduce_sub(float4 a) {
  a.x += __shfl_xor(a.x, 16, 64); a.y += __shfl_xor(a.y, 16, 64);
  a.z += __shfl_xor(a.z, 16, 64); a.w += __shfl_xor(a.w, 16, 64);
  a.x += __shfl_xor(a.x, 32, 64); a.y += __shfl_xor(a.y, 32, 64);
  a.z += __shfl_xor(a.z, 32, 64); a.w += __shfl_xor(a.w, 32, 64);
  return a;
}

// gather sum of csr rows [beg, beg+d) of h into s_row (one wave, 4 edges/iter)
__device__ __forceinline__ void wave_gather_row(const float* __restrict__ h,
                                                const int* __restrict__ csr,
                                                int beg, int d, int sub, int ch,
                                                float* __restrict__ s_row) {
  float4 acc = {0.f, 0.f, 0.f, 0.f};
  int i = sub;
  for (; i + 4 < d; i += 8) {
    int s0 = csr[beg + i];
    int s1 = csr[beg + i + 4];
    float4 v0 = ((const float4*)(h + (size_t)s0 * FEAT))[ch];
    float4 v1 = ((const float4*)(h + (size_t)s1 * FEAT))[ch];
    acc.x += v0.x + v1.x; acc.y += v0.y + v1.y;
    acc.z += v0.z + v1.z; acc.w += v0.w + v1.w;
  }
  if (i < d) {
    int s0 = csr[beg + i];
    float4 v0 = ((const float4*)(h + (size_t)s0 * FEAT))[ch];
    acc.x += v0.x; acc.y += v0.y; acc.z += v0.z; acc.w += v0.w;
  }
  acc = reduce_sub(acc);
  if (sub == 0) *(float4*)&s_row[ch * 4] = acc;
}

// ---------------- fused layer: out = elu(h@Wroot + (A h)@Wrel + b) ----------
// Block = 256 threads, 64 nodes. agg lives only in LDS.
__global__ void layer_fused_kernel(const float* __restrict__ h,
                                   const int* __restrict__ row_start,
                                   const int* __restrict__ deg,
                                   const int* __restrict__ csr,
                                   const float* __restrict__ w_root,
                                   const float* __restrict__ w_rel,
                                   const float* __restrict__ bias,
                                   float* __restrict__ out, int n) {
  __shared__ float s_h[64][STRIDE];
  __shared__ float s_a[64][STRIDE];
  const int tid = threadIdx.x;
  const int wv = __builtin_amdgcn_readfirstlane(tid >> 6);
  const int lane = tid & 63;
  const int sub = lane >> 4;
  const int ch = lane & 15;
  const int base = blockIdx.x * 64;

  // phase B: stage own h rows (coalesced float4)
  for (int it = 0; it < 4; ++it) {
    int idx = tid + it * 256;           // 0..1023
    int nl = idx >> 4, c = idx & 15;
    int node = base + nl;
    if (node < n) {
      float4 v = ((const float4*)(h + (size_t)node * FEAT))[c];
      *(float4*)&s_h[nl][c * 4] = v;
    }
  }

  // phase A: gather agg rows into LDS (wave wv handles nodes wv*16..+15)
  for (int t = 0; t < 16; ++t) {
    int nl = wv * 16 + t;
    int node = base + nl;
    if (node >= n) break;
    int beg = row_start[node];
    int d = deg[node];
    wave_gather_row(h, csr, beg, d, sub, ch, &s_a[nl][0]);
  }
  __syncthreads();

  // phase C: lane = node, wave computes output slice [wv*16, wv*16+16)
  const int jb = wv * 16;
  float acc[16];
#pragma unroll
  for (int jj = 0; jj < 16; ++jj) acc[jj] = bias[jb + jj];

  for (int k = 0; k < FEAT; k += 4) {
    const float4 hv = *(const float4*)&s_h[lane][k];
    const float4 av = *(const float4*)&s_a[lane][k];
    const float hk[4] = {hv.x, hv.y, hv.z, hv.w};
    const float ak[4] = {av.x, av.y, av.z, av.w};
#pragma unroll
    for (int kk = 0; kk < 4; ++kk) {
      const float* wr = w_root + (k + kk) * FEAT + jb;
      const float* wl = w_rel + (k + kk) * FEAT + jb;
#pragma unroll
      for (int jj = 0; jj < 16; ++jj)
        acc[jj] += hk[kk] * wr[jj] + ak[kk] * wl[jj];
    }
  }
  __syncthreads();

  // epilogue: ELU, stage via s_h, coalesced store
#pragma unroll
  for (int jj = 0; jj < 16; ++jj) {
    float a = acc[jj];
    s_h[lane][jb + jj] = a > 0.f ? a : (__expf(a) - 1.f);
  }
  __syncthreads();
  for (int it = 0; it < 4; ++it) {
    int idx = tid + it * 256;
    int nl = idx >> 4, c = idx & 15;
    int node = base + nl;
    if (node < n) {
      *(float4*)(out + (size_t)node * FEAT + c * 4) = *(const float4*)&s_h[nl][c * 4];
    }
  }
}

// ---------------- fused pooling + MLP head ----------------
// Block = 256 threads, 64 sets. pooled lives only in LDS.
__global__ void pool_mlp_kernel(const float* __restrict__ h,
                                const int* __restrict__ row_start,
                                const int* __restrict__ deg,
                                const int* __restrict__ csr,
                                const float* __restrict__ fc1_w, const float* __restrict__ fc1_b,
                                const float* __restrict__ fc2_w, const float* __restrict__ fc2_b,
                                const float* __restrict__ fc3_w, const float* __restrict__ fc3_b,
                                float* __restrict__ out, int nsets) {
  __shared__ float s_p[64][STRIDE];
  __shared__ float s_t1[64][STRIDE];
  __shared__ float s_t2[64][36];
  const int tid = threadIdx.x;
  const int wv = __builtin_amdgcn_readfirstlane(tid >> 6);
  const int lane = tid & 63;
  const int sub = lane >> 4;
  const int ch = lane & 15;
  const int base = blockIdx.x * 64;

  // gather pooled rows
  for (int t = 0; t < 16; ++t) {
    int nl = wv * 16 + t;
    int s = base + nl;
    if (s >= nsets) break;
    int beg = row_start[s];
    int d = deg[s];
    wave_gather_row(h, csr, beg, d, sub, ch, &s_p[nl][0]);
  }
  __syncthreads();

  // fc1 (64->64) + ELU
  {
    const int jb = wv * 16;
    float acc[16];
#pragma unroll
    for (int jj = 0; jj < 16; ++jj) acc[jj] = fc1_b[jb + jj];
    for (int k = 0; k < FEAT; k += 4) {
      const float4 pv = *(const float4*)&s_p[lane][k];
      const float pk[4] = {pv.x, pv.y, pv.z, pv.w};
#pragma unroll
      for (int kk = 0; kk < 4; ++kk) {
        const float* w = fc1_w + (k + kk) * FEAT + jb;
#pragma unroll
        for (int jj = 0; jj < 16; ++jj) acc[jj] += pk[kk] * w[jj];
      }
    }
#pragma unroll
    for (int jj = 0; jj < 16; ++jj) {
      float a = acc[jj];
      s_t1[lane][jb + jj] = a > 0.f ? a : (__expf(a) - 1.f);
    }
  }
  __syncthreads();

  // fc2 (64->32) + ELU
  {
    const int jb = wv * 8;
    float acc[8];
#pragma unroll
    for (int jj = 0; jj < 8; ++jj) acc[jj] = fc2_b[jb + jj];
    for (int k = 0; k < FEAT; k += 4) {
      const float4 tv = *(const float4*)&s_t1[lane][k];
      const float tk[4] = {tv.x, tv.y, tv.z, tv.w};
#pragma unroll
      for (int kk = 0; kk < 4; ++kk) {
        const float* w = fc2_w + (k + kk) * 32 + jb;
#pragma unroll
        for (int jj = 0; jj < 8; ++jj) acc[jj] += tk[kk] * w[jj];
      }
    }
#pragma unroll
    for (int jj = 0; jj < 8; ++jj) {
      float a = acc[jj];
      s_t2[lane][jb + jj] = a > 0.f ? a : (__expf(a) - 1.f);
    }
  }
  __syncthreads();

  // fc3 (32->2) + log_softmax, wave 0 handles all 64 sets
  if (wv == 0) {
    int s = base + lane;
    if (s < nsets) {
      float a0 = fc3_b[0], a1 = fc3_b[1];
      for (int k = 0; k < 32; k += 4) {
        const float4 tv = *(const float4*)&s_t2[lane][k];
        const float tk[4] = {tv.x, tv.y, tv.z, tv.w};
#pragma unroll
        for (int kk = 0; kk < 4; ++kk) {
          a0 += tk[kk] * fc3_w[(k + kk) * 2 + 0];
          a1 += tk[kk] * fc3_w[(k + kk) * 2 + 1];
        }
      }
      float m = fmaxf(a0, a1);
      float lse = m + logf(__expf(a0 - m) + __expf(a1 - m));
      float2 r = {a0 - lse, a1 - lse};
      *(float2*)(out + (size_t)s * 2) = r;
    }
  }
}

extern "C" void kernel_launch(void* const* d_in, const int* in_sizes, int n_in,
                              void* d_out, int out_size, void* d_ws, size_t ws_size,
                              hipStream_t stream) {
  const float* x        = (const float*)d_in[0];
  const int* edge_src   = (const int*)d_in[1];
  const int* edge_dst   = (const int*)d_in[2];
  const int* gather_idx = (const int*)d_in[3];
  const int* seg_idx    = (const int*)d_in[4];
  const float* w_root0  = (const float*)d_in[5];
  const float* w_rel0   = (const float*)d_in[6];
  const float* b0       = (const float*)d_in[7];
  const float* w_root_h = (const float*)d_in[8];
  const float* w_rel_h  = (const float*)d_in[9];
  const float* b_h      = (const float*)d_in[10];
  const float* fc1_w    = (const float*)d_in[11];
  const float* fc1_b    = (const float*)d_in[12];
  const float* fc2_w    = (const float*)d_in[13];
  const float* fc2_b    = (const float*)d_in[14];
  const float* fc3_w    = (const float*)d_in[15];
  const float* fc3_b    = (const float*)d_in[16];

  const int N = in_sizes[0] / FEAT;
  const int E = in_sizes[1];
  const int A = in_sizes[3];
  const int S = out_size / 2;

  size_t row_bytes = (size_t)N * FEAT * sizeof(float);

  char* ws = (char*)d_ws;
  size_t off = 0;
  float* buf1   = (float*)(ws + off); off += row_bytes;
  float* buf2   = (float*)(ws + off); off += row_bytes;
  int* csr_e    = (int*)(ws + off); off += (size_t)E * 4;
  int* deg_e    = (int*)(ws + off); off += (size_t)N * 4;
  int* rs_e     = (int*)(ws + off); off += (size_t)N * 4;
  int* cur_e    = (int*)(ws + off); off += (size_t)N * 4;
  int* csr_p    = (int*)(ws + off); off += (size_t)A * 4;
  int* deg_p    = (int*)(ws + off); off += (size_t)S * 4;
  int* rs_p     = (int*)(ws + off); off += (size_t)S * 4;
  int* cur_p    = (int*)(ws + off); off += (size_t)S * 4;
  int* bsums_e  = (int*)(ws + off); off += 256 * 4;
  int* bsums_p  = (int*)(ws + off); off += 256 * 4;

  dim3 blk(256);
  int nb_e = (N + SCHUNK - 1) / SCHUNK;
  int nb_p = (S + SCHUNK - 1) / SCHUNK;

  // ---- build edge CSR (dst-major) ----
  hipMemsetAsync(deg_e, 0, (size_t)N * 4, stream);
  count_kernel<<<(E + 255) / 256, blk, 0, stream>>>(edge_dst, deg_e, E);
  scan1_kernel<<<nb_e, blk, 0, stream>>>(deg_e, rs_e, bsums_e, N);
  scan2_kernel<<<1, blk, 0, stream>>>(bsums_e, nb_e);
  scan3_kernel<<<(N + 255) / 256, blk, 0, stream>>>(rs_e, bsums_e, cur_e, N);
  fill_kernel<<<(E + 255) / 256, blk, 0, stream>>>(edge_src, edge_dst, cur_e, csr_e, E);

  // ---- build pool CSR (seg-major) ----
  hipMemsetAsync(deg_p, 0, (size_t)S * 4, stream);
  count_kernel<<<(A + 255) / 256, blk, 0, stream>>>(seg_idx, deg_p, A);
  scan1_kernel<<<nb_p, blk, 0, stream>>>(deg_p, rs_p, bsums_p, S);
  scan2_kernel<<<1, blk, 0, stream>>>(bsums_p, nb_p);
  scan3_kernel<<<(S + 255) / 256, blk, 0, stream>>>(rs_p, bsums_p, cur_p, S);
  fill_kernel<<<(A + 255) / 256, blk, 0, stream>>>(gather_idx, seg_idx, cur_p, csr_p, A);

  int lgrid = (N + 63) / 64;
  int pgrid = (S + 63) / 64;

  // ---- 3 fused GraphConv layers ----
  layer_fused_kernel<<<lgrid, blk, 0, stream>>>(x, rs_e, deg_e, csr_e,
                                                w_root0, w_rel0, b0, buf1, N);
  layer_fused_kernel<<<lgrid, blk, 0, stream>>>(buf1, rs_e, deg_e, csr_e,
                                                w_root_h, w_rel_h, b_h, buf2, N);
  layer_fused_kernel<<<lgrid, blk, 0, stream>>>(buf2, rs_e, deg_e, csr_e,
                                                w_root_h + FEAT * FEAT, w_rel_h + FEAT * FEAT,
                                                b_h + FEAT, buf1, N);

  // ---- fused pooling + MLP head + log_softmax ----
  pool_mlp_kernel<<<pgrid, blk, 0, stream>>>(buf1, rs_p, deg_p, csr_p,
                                             fc1_w, fc1_b, fc2_w, fc2_b, fc3_w, fc3_b,
                                             (float*)d_out, S);
}